// Round 13
// baseline (376.793 us; speedup 1.0000x reference)
//
#include <hip/hip_runtime.h>
#include <hip/hip_bf16.h>

typedef __hip_bfloat16 bf16;
typedef __attribute__((ext_vector_type(8))) short short8;   // 8 bf16 MFMA frag
typedef __attribute__((ext_vector_type(4))) float f32x4;    // MFMA acc
typedef __attribute__((ext_vector_type(8))) unsigned short u16x8;
typedef __attribute__((ext_vector_type(4))) unsigned short u16x4;

#define HWSZ 4096
#define CH 512
#define BATCH 4
#define NGROUPS 32
#define CPG 16
#define PER ((size_t)CH * HWSZ)

// async global->LDS, 16 B per lane; LDS dest is wave-uniform base + lane*16
#define GLL16(gp, lp)                                                         \
  __builtin_amdgcn_global_load_lds(                                           \
      (const __attribute__((address_space(1))) void*)(gp),                    \
      (__attribute__((address_space(3))) void*)(lp), 16, 0, 0)

__device__ __forceinline__ float b2f(bf16 v) { return __bfloat162float(v); }
__device__ __forceinline__ bf16 f2b(float v) { return __float2bfloat16(v); }

// ---------------- GN stage 1: partial sums, 8 chunks per (b,g) ----------------
__global__ void gn_part_kernel(const float* __restrict__ x, float2* __restrict__ gpart) {
  int bg = blockIdx.x >> 3, chunk = blockIdx.x & 7;
  size_t base = (size_t)bg * (CPG * HWSZ) + (size_t)chunk * 8192;
  int tid = threadIdx.x;
  float s = 0.f, ss = 0.f;
  const float4* xp = (const float4*)(x + base);
#pragma unroll
  for (int it = 0; it < 8; ++it) {
    float4 v = xp[tid + it * 256];
    s += v.x + v.y + v.z + v.w;
    ss += v.x * v.x + v.y * v.y + v.z * v.z + v.w * v.w;
  }
  __shared__ float rs[256], rss[256];
  rs[tid] = s; rss[tid] = ss;
  __syncthreads();
  for (int off = 128; off > 0; off >>= 1) {
    if (tid < off) { rs[tid] += rs[tid + off]; rss[tid] += rss[tid + off]; }
    __syncthreads();
  }
  if (tid == 0) gpart[blockIdx.x] = make_float2(rs[0], rss[0]);
}

// ---------------- GN stage 2: per-(b,c) scale/shift ----------------
__global__ void gn_final_kernel(const float2* __restrict__ gpart,
                                const float* __restrict__ gw, const float* __restrict__ gb,
                                float* __restrict__ sca, float* __restrict__ shf) {
  int idx = blockIdx.x * 256 + threadIdx.x;
  int b = idx >> 9, c = idx & 511;
  int bg = b * NGROUPS + (c >> 4);
  float s = 0.f, ss = 0.f;
#pragma unroll
  for (int t = 0; t < 8; ++t) {
    float2 p = gpart[bg * 8 + t];
    s += p.x; ss += p.y;
  }
  const float N = (float)(CPG * HWSZ);
  float mu = s / N;
  float var = ss / N - mu * mu;
  float inv = rsqrtf(var + 1e-6f);
  float a = inv * gw[c];
  sca[idx] = a;
  shf[idx] = gb[c] - mu * a;
}

// ---------------- weights f32 -> bf16 (once) ----------------
__global__ void wconv_kernel(const float* __restrict__ qw, const float* __restrict__ kw,
                             const float* __restrict__ vw,
                             bf16* __restrict__ wq, bf16* __restrict__ wk, bf16* __restrict__ wv) {
  int i = blockIdx.x * 256 + threadIdx.x;
  wq[i] = f2b(qw[i]);
  wk[i] = f2b(kw[i]);
  wv[i] = f2b(vw[i]);
}

// ---------------- h_apply: hT[p][c] = bf16(sca[c]*x[b,c,p]+shf[c]) (transpose) -------
__global__ void h_apply_kernel(const float* __restrict__ x, const float* __restrict__ sca,
                               const float* __restrict__ shf, bf16* __restrict__ hT, int b0) {
  int p0 = blockIdx.x * 64, c0 = blockIdx.y * 64;
  int b = b0 + blockIdx.z;
  bf16* hTb = hT + (size_t)blockIdx.z * PER;
  __shared__ bf16 lt[64][66];
  int t = threadIdx.x;
  int pp = (t & 15) * 4, ccb = t >> 4;
#pragma unroll
  for (int it = 0; it < 4; ++it) {
    int cc = ccb + it * 16;
    int c = c0 + cc;
    float a = sca[b * CH + c], s = shf[b * CH + c];
    const float4 xv = *(const float4*)(x + ((size_t)(b * CH + c)) * HWSZ + p0 + pp);
    lt[cc][pp] = f2b(a * xv.x + s);
    lt[cc][pp + 1] = f2b(a * xv.y + s);
    lt[cc][pp + 2] = f2b(a * xv.z + s);
    lt[cc][pp + 3] = f2b(a * xv.w + s);
  }
  __syncthreads();
  int cc = (t & 15) * 4;
#pragma unroll
  for (int it = 0; it < 4; ++it) {
    int pr = (t >> 4) + it * 16;
    u16x4 o;
#pragma unroll
    for (int j = 0; j < 4; ++j) o[j] = *(const unsigned short*)&lt[cc + j][pr];
    *(u16x4*)(hTb + (size_t)(p0 + pr) * CH + c0 + cc) = o;
  }
}

// ======================= shared pipelined GEMM skeleton =======================
// r1/r6-verified skeleton (session best 351us total, 0 bank conflicts):
// 128x128 tile, BK=64, 2x32KB double-buffered LDS, counted vmcnt(8).
// Staging: linear LDS dest + XOR-swizzled GLOBAL source granule:
// LDS[row][g] = global[row][g ^ (row&7)] (rows are 128 B = 8 x 16B granules);
// fragment ds_read_b128 applies the same XOR -> conflict-free.
// Pipeline per K-step t: issue STAGE(t+1) -> s_waitcnt vmcnt(8) -> s_barrier
// -> ds_read+MFMA -> s_barrier. vmcnt(0) only on the final peel.

__device__ __forceinline__ void mm_step(const bf16* la, const bf16* lb,
                                        f32x4 acc[4][4], int wm, int wn,
                                        int quad, int tm) {
#pragma unroll
  for (int kk = 0; kk < 2; ++kk) {
    const int go = ((kk * 4 + quad) ^ (tm & 7)) * 8;  // swizzled granule offset
    short8 aF[4], bF[4];
#pragma unroll
    for (int mt = 0; mt < 4; ++mt) {
      aF[mt] = *(const short8*)(la + (wm + mt * 16 + tm) * 64 + go);
      bF[mt] = *(const short8*)(lb + (wn + mt * 16 + tm) * 64 + go);
    }
#pragma unroll
    for (int mt = 0; mt < 4; ++mt)
#pragma unroll
      for (int nt = 0; nt < 4; ++nt)
        acc[mt][nt] = __builtin_amdgcn_mfma_f32_16x16x32_bf16(aF[mt], bF[nt],
                                                              acc[mt][nt], 0, 0, 0);
  }
}

#define MFMA_VARS()                                   \
  int tid = threadIdx.x;                              \
  int l = tid & 63, w = tid >> 6;                     \
  int quad = l >> 4, tm = l & 15;                     \
  int wm = (w & 1) * 64, wn = (w >> 1) * 64;          \
  int rr = l >> 3;                                    \
  int swz = ((l & 7) ^ rr) * 8;                       \
  bf16* stbase = smem + w * 2048

#define MSTAGE(bufsel, koff)                          \
  do {                                                \
    bf16* _d = stbase + (bufsel) * 16384;             \
    GLL16(sA0 + (koff), _d);                          \
    GLL16(sA1 + (koff), _d + 512);                    \
    GLL16(sA2 + (koff), _d + 1024);                   \
    GLL16(sA3 + (koff), _d + 1536);                   \
    GLL16(sB0 + (koff), _d + 8192);                   \
    GLL16(sB1 + (koff), _d + 8704);                   \
    GLL16(sB2 + (koff), _d + 9216);                   \
    GLL16(sB3 + (koff), _d + 9728);                   \
  } while (0)

#define MKLOOP(NS)                                                       \
  do {                                                                   \
    MSTAGE(0, 0);                                                        \
    for (int _t = 0; _t < (NS); ++_t) {                                  \
      if (_t + 1 < (NS)) {                                               \
        MSTAGE((_t + 1) & 1, (_t + 1) * 64);                             \
        asm volatile("s_waitcnt vmcnt(8)" ::: "memory");                 \
      } else {                                                           \
        asm volatile("s_waitcnt vmcnt(0)" ::: "memory");                 \
      }                                                                  \
      __builtin_amdgcn_s_barrier();                                      \
      mm_step(smem + (_t & 1) * 16384, smem + (_t & 1) * 16384 + 8192,   \
              acc, wm, wn, quad, tm);                                    \
      __builtin_amdgcn_s_barrier();                                      \
    }                                                                    \
  } while (0)

// ---------------- QKV via MFMA (NT), pipelined BK=64, batched ----------------
__global__ __launch_bounds__(256) void qkv_mfma(const bf16* __restrict__ hT,
                                                const bf16* __restrict__ wq,
                                                const bf16* __restrict__ wk,
                                                const bf16* __restrict__ wv,
                                                const float* __restrict__ qb,
                                                const float* __restrict__ kb,
                                                const float* __restrict__ vb,
                                                bf16* __restrict__ qT, bf16* __restrict__ kT,
                                                bf16* __restrict__ v) {
  int p0 = blockIdx.x * 128;
  int o0 = blockIdx.y * 128;
  int bz = blockIdx.z / 3, z = blockIdx.z % 3;
  const bf16* W = z == 0 ? wq : (z == 1 ? wk : wv);
  const float* bias = z == 0 ? qb : (z == 1 ? kb : vb);
  const bf16* hTb = hT + (size_t)bz * PER;
  __shared__ __align__(16) bf16 smem[32768];  // 2 bufs x (A 8192 | B 8192)
  MFMA_VARS();
  const bf16* sA0 = hTb + (size_t)(p0 + w * 32 + rr) * CH + swz;
  const bf16* sA1 = sA0 + (size_t)8 * CH;
  const bf16* sA2 = sA0 + (size_t)16 * CH;
  const bf16* sA3 = sA0 + (size_t)24 * CH;
  const bf16* sB0 = W + (size_t)(o0 + w * 32 + rr) * CH + swz;
  const bf16* sB1 = sB0 + (size_t)8 * CH;
  const bf16* sB2 = sB0 + (size_t)16 * CH;
  const bf16* sB3 = sB0 + (size_t)24 * CH;
  f32x4 acc[4][4] = {};
  MKLOOP(CH / 64);
  if (z < 2) {
    bf16* outT = (z == 0 ? qT : kT) + (size_t)bz * PER;
#pragma unroll
    for (int nt = 0; nt < 4; ++nt) {
      int o = o0 + wn + nt * 16 + tm;
      float bv = bias[o];
#pragma unroll
      for (int mt = 0; mt < 4; ++mt)
#pragma unroll
        for (int r = 0; r < 4; ++r) {
          int p = p0 + wm + mt * 16 + quad * 4 + r;
          outT[(size_t)p * CH + o] = f2b(acc[mt][nt][r] + bv);
        }
    }
  } else {
    // LDS transpose epilogue: v[o][p]
    bf16* vv = v + (size_t)bz * PER;
    bf16* lt = smem;  // 64 x 136 = 8704 elems (fits in 32768)
    for (int chunk = 0; chunk < 2; ++chunk) {
      __syncthreads();
      if (wn == chunk * 64) {
#pragma unroll
        for (int nt = 0; nt < 4; ++nt) {
          int o = o0 + wn + nt * 16 + tm;
          float bv = bias[o];
#pragma unroll
          for (int mt = 0; mt < 4; ++mt)
#pragma unroll
            for (int r = 0; r < 4; ++r)
              lt[(nt * 16 + tm) * 136 + wm + mt * 16 + quad * 4 + r] = f2b(acc[mt][nt][r] + bv);
        }
      }
      __syncthreads();
      int oo = tid >> 2, ppb = (tid & 3) * 32;
      bf16* dst = vv + (size_t)(o0 + chunk * 64 + oo) * HWSZ + p0 + ppb;
      const bf16* src = lt + oo * 136 + ppb;
#pragma unroll
      for (int q4 = 0; q4 < 4; ++q4)
        *(u16x8*)(dst + q4 * 8) = *(const u16x8*)(src + q4 * 8);
    }
  }
}

// ---------------- S via MFMA (NT), pipelined BK=64, fused exp + row-sum, batched -----
// attn[il][j] = exp(scale * sum_c qT[i][c] kT[j][c]); lsum[il] += row partial sums
// (no max-subtraction: |s*scale| <~ 1.2 for this input distribution — r10-validated)
// r13: attn written via LDS-gather epilogue — r12 PMC showed WRITE_SIZE 147MB vs
// 64MB ideal (2.3x amplification: per-lane 2B scatter = 32B row fragments).
// Stage exp() into lt[128][136] then store 256B-contiguous row segments.
__global__ __launch_bounds__(256) void s_mfma(const bf16* __restrict__ qT,
                                              const bf16* __restrict__ kT,
                                              bf16* __restrict__ attn,
                                              float* __restrict__ lsum) {
  int j0 = blockIdx.x * 128;
  int il0 = blockIdx.y * 128;
  int bz = blockIdx.z;
  const bf16* qTb = qT + (size_t)bz * PER;
  const bf16* kTb = kT + (size_t)bz * PER;
  bf16* attnb = attn + (size_t)bz * HWSZ * HWSZ;
  float* lsumb = lsum + (size_t)bz * HWSZ;
  __shared__ __align__(16) bf16 smem[32768];
  MFMA_VARS();
  const bf16* sA0 = qTb + (size_t)(il0 + w * 32 + rr) * CH + swz;
  const bf16* sA1 = sA0 + (size_t)8 * CH;
  const bf16* sA2 = sA0 + (size_t)16 * CH;
  const bf16* sA3 = sA0 + (size_t)24 * CH;
  const bf16* sB0 = kTb + (size_t)(j0 + w * 32 + rr) * CH + swz;
  const bf16* sB1 = sB0 + (size_t)8 * CH;
  const bf16* sB2 = sB0 + (size_t)16 * CH;
  const bf16* sB3 = sB0 + (size_t)24 * CH;
  f32x4 acc[4][4] = {};
  MKLOOP(CH / 64);
  const float scale = 0.044194173824159216f;  // 512^-0.5
  // K-loop's final barrier has retired all LDS reads -> safe to reuse smem.
  bf16* lt = smem;  // 128 x 136 bf16 = 34816 B (of 65536)
#pragma unroll
  for (int mt = 0; mt < 4; ++mt)
#pragma unroll
    for (int r = 0; r < 4; ++r) {
      int lrow = wm + mt * 16 + quad * 4 + r;
      int il = il0 + lrow;
      float rs = 0.f;
#pragma unroll
      for (int nt = 0; nt < 4; ++nt) {
        float p = __expf(acc[mt][nt][r] * scale);
        rs += p;
        lt[lrow * 136 + wn + nt * 16 + tm] = f2b(p);
      }
      rs += __shfl_xor(rs, 1);
      rs += __shfl_xor(rs, 2);
      rs += __shfl_xor(rs, 4);
      rs += __shfl_xor(rs, 8);
      if (tm == 0) atomicAdd(&lsumb[il], rs);
    }
  __syncthreads();
  // Coalesced store: 16 lanes x u16x8 = 256 B contiguous per row, 4 rows/wave op.
  int orow = tid >> 4, ocol = (tid & 15) * 8;
#pragma unroll
  for (int it = 0; it < 8; ++it) {
    int rrow = orow + it * 16;
    *(u16x8*)(attnb + (size_t)(il0 + rrow) * HWSZ + j0 + ocol) =
        *(const u16x8*)(lt + rrow * 136 + ocol);
  }
}

// ---------------- A via MFMA + split-K atomics, pipelined BK=64, batched -------------
__global__ __launch_bounds__(256) void a_mfma(const bf16* __restrict__ v,
                                              const bf16* __restrict__ attn,
                                              float* __restrict__ acc_out,
                                              int KC, int ksplit) {
  int il0 = blockIdx.x * 128;
  int c00 = blockIdx.y * 128;
  int bz = blockIdx.z / ksplit;
  int kbase = (blockIdx.z % ksplit) * KC;
  const bf16* vb = v + (size_t)bz * PER;
  const bf16* attnb = attn + (size_t)bz * HWSZ * HWSZ;
  float* accb = acc_out + (size_t)bz * CH * HWSZ;
  __shared__ __align__(16) bf16 smem[32768];
  MFMA_VARS();
  const bf16* sA0 = vb + (size_t)(c00 + w * 32 + rr) * HWSZ + kbase + swz;
  const bf16* sA1 = sA0 + (size_t)8 * HWSZ;
  const bf16* sA2 = sA0 + (size_t)16 * HWSZ;
  const bf16* sA3 = sA0 + (size_t)24 * HWSZ;
  const bf16* sB0 = attnb + (size_t)(il0 + w * 32 + rr) * HWSZ + kbase + swz;
  const bf16* sB1 = sB0 + (size_t)8 * HWSZ;
  const bf16* sB2 = sB0 + (size_t)16 * HWSZ;
  const bf16* sB3 = sB0 + (size_t)24 * HWSZ;
  f32x4 acc[4][4] = {};
  MKLOOP(KC / 64);
#pragma unroll
  for (int mt = 0; mt < 4; ++mt)
#pragma unroll
    for (int nt = 0; nt < 4; ++nt)
#pragma unroll
      for (int r = 0; r < 4; ++r) {
        int c = c00 + wm + mt * 16 + quad * 4 + r;
        int il = il0 + wn + nt * 16 + tm;
        atomicAdd(&accb[(size_t)c * HWSZ + il], acc[mt][nt][r]);
      }
}

// ---------------- out[b,c,i] = x + acc/lsum, batched ----------------
__global__ void add_kernel(const float* __restrict__ x, const float* __restrict__ acc,
                           const float* __restrict__ lsum, float* __restrict__ out, int b0) {
  int idx = blockIdx.x * 256 + threadIdx.x;
  int b = b0 + blockIdx.y;
  const float* accb = acc + (size_t)blockIdx.y * CH * HWSZ;
  const float* lsumb = lsum + (size_t)blockIdx.y * HWSZ;
  int c = idx >> 10;               // 1024 float4 per row of HWSZ
  int r4 = (idx & 1023) * 4;
  size_t g = ((size_t)(b * CH + c)) * HWSZ + r4;
  const float4 xv = *(const float4*)(x + g);
  const float4 av = *(const float4*)(accb + (size_t)c * HWSZ + r4);
  const float4 lv = *(const float4*)(lsumb + r4);
  float4 o;
  o.x = xv.x + av.x / lv.x;
  o.y = xv.y + av.y / lv.y;
  o.z = xv.z + av.z / lv.z;
  o.w = xv.w + av.w / lv.w;
  *(float4*)(out + g) = o;
}

extern "C" void kernel_launch(void* const* d_in, const int* in_sizes, int n_in,
                              void* d_out, int out_size, void* d_ws, size_t ws_size,
                              hipStream_t stream) {
  const float* x   = (const float*)d_in[0];
  const float* gnw = (const float*)d_in[1];
  const float* gnb = (const float*)d_in[2];
  const float* qw  = (const float*)d_in[3];
  const float* qb  = (const float*)d_in[4];
  const float* kw  = (const float*)d_in[5];
  const float* kb  = (const float*)d_in[6];
  const float* vw  = (const float*)d_in[7];
  const float* vb  = (const float*)d_in[8];
  float* out = (float*)d_out;

  char* ws = (char*)d_ws;
  float* sca = (float*)ws;
  float* shf = sca + BATCH * CH;
  float2* gpart = (float2*)(ws + 16384);
  const size_t wsz = (size_t)CH * CH;
  bf16* wqb = (bf16*)(ws + 32768);
  bf16* wkb = wqb + wsz;
  bf16* wvb = wkb + wsz;
  char* dyn = (char*)(wvb + wsz);
  size_t base_used = (size_t)(dyn - ws);
  // per-live-batch: hT/qT/kT/v (4*PER bf16) + attn (HWSZ^2 bf16) + acc (CH*HWSZ f32) + lsum
  size_t perb = 4 * PER * sizeof(bf16) + (size_t)HWSZ * HWSZ * sizeof(bf16) +
                (size_t)CH * HWSZ * sizeof(float) + (size_t)HWSZ * sizeof(float);
  int nb = (int)(((long long)ws_size - (long long)base_used) / (long long)perb);
  if (nb < 1) nb = 1;
  if (nb > BATCH) nb = BATCH;
  bf16* hT = (bf16*)dyn;
  bf16* qT = hT + (size_t)nb * PER;
  bf16* kT = qT + (size_t)nb * PER;
  bf16* v  = kT + (size_t)nb * PER;
  bf16* attn = v + (size_t)nb * PER;
  float* acc = (float*)(attn + (size_t)nb * HWSZ * HWSZ);
  float* lsum = acc + (size_t)nb * CH * HWSZ;

  gn_part_kernel<<<dim3(BATCH * NGROUPS * 8), 256, 0, stream>>>(x, gpart);
  gn_final_kernel<<<dim3(8), 256, 0, stream>>>(gpart, gnw, gnb, sca, shf);
  wconv_kernel<<<dim3(wsz / 256), 256, 0, stream>>>(qw, kw, vw, wqb, wkb, wvb);
  for (int b0 = 0; b0 < BATCH; b0 += nb) {
    int nbc = BATCH - b0 < nb ? BATCH - b0 : nb;
    h_apply_kernel<<<dim3(HWSZ / 64, CH / 64, nbc), 256, 0, stream>>>(x, sca, shf, hT, b0);
    qkv_mfma<<<dim3(HWSZ / 128, CH / 128, 3 * nbc), 256, 0, stream>>>(hT, wqb, wkb, wvb,
                                                                      qb, kb, vb, qT, kT, v);
    hipMemsetAsync(acc, 0, (size_t)nbc * CH * HWSZ * sizeof(float), stream);
    hipMemsetAsync(lsum, 0, (size_t)nbc * HWSZ * sizeof(float), stream);
    // ksplit=4 -> KC=1024 -> 16 K-steps of BK=64 (r1/r6's proven per-block shape);
    // r12 A/B: ksplit=2 neutral-to-worse (FETCH 133->195MB, same dur) — keep 4.
    int ksplit = 1024 / (32 * 4 * nbc);
    if (ksplit < 1) ksplit = 1;
    if (ksplit > 4) ksplit = 4;
    while (ksplit & (ksplit - 1)) --ksplit;
    int KC = HWSZ / ksplit;
    s_mfma<<<dim3(HWSZ / 128, HWSZ / 128, nbc), 256, 0, stream>>>(qT, kT, attn, lsum);
    a_mfma<<<dim3(HWSZ / 128, CH / 128, ksplit * nbc), 256, 0, stream>>>(v, attn, acc, KC, ksplit);
    add_kernel<<<dim3((CH * HWSZ) / 1024, nbc), 256, 0, stream>>>(x, acc, lsum, out, b0);
  }
}

// Round 14
// 354.239 us; speedup vs baseline: 1.0637x; 1.0637x over previous
//
#include <hip/hip_runtime.h>
#include <hip/hip_bf16.h>

typedef __hip_bfloat16 bf16;
typedef __attribute__((ext_vector_type(8))) short short8;   // 8 bf16 MFMA frag
typedef __attribute__((ext_vector_type(4))) float f32x4;    // MFMA acc
typedef __attribute__((ext_vector_type(8))) unsigned short u16x8;
typedef __attribute__((ext_vector_type(4))) unsigned short u16x4;

#define HWSZ 4096
#define CH 512
#define BATCH 4
#define NGROUPS 32
#define CPG 16
#define PER ((size_t)CH * HWSZ)

// async global->LDS, 16 B per lane; LDS dest is wave-uniform base + lane*16
#define GLL16(gp, lp)                                                         \
  __builtin_amdgcn_global_load_lds(                                           \
      (const __attribute__((address_space(1))) void*)(gp),                    \
      (__attribute__((address_space(3))) void*)(lp), 16, 0, 0)

__device__ __forceinline__ float b2f(bf16 v) { return __bfloat162float(v); }
__device__ __forceinline__ bf16 f2b(float v) { return __float2bfloat16(v); }

// ---------------- GN stage 1: partial sums, 8 chunks per (b,g) ----------------
__global__ void gn_part_kernel(const float* __restrict__ x, float2* __restrict__ gpart) {
  int bg = blockIdx.x >> 3, chunk = blockIdx.x & 7;
  size_t base = (size_t)bg * (CPG * HWSZ) + (size_t)chunk * 8192;
  int tid = threadIdx.x;
  float s = 0.f, ss = 0.f;
  const float4* xp = (const float4*)(x + base);
#pragma unroll
  for (int it = 0; it < 8; ++it) {
    float4 v = xp[tid + it * 256];
    s += v.x + v.y + v.z + v.w;
    ss += v.x * v.x + v.y * v.y + v.z * v.z + v.w * v.w;
  }
  __shared__ float rs[256], rss[256];
  rs[tid] = s; rss[tid] = ss;
  __syncthreads();
  for (int off = 128; off > 0; off >>= 1) {
    if (tid < off) { rs[tid] += rs[tid + off]; rss[tid] += rss[tid + off]; }
    __syncthreads();
  }
  if (tid == 0) gpart[blockIdx.x] = make_float2(rs[0], rss[0]);
}

// ---------------- GN stage 2: per-(b,c) scale/shift ----------------
__global__ void gn_final_kernel(const float2* __restrict__ gpart,
                                const float* __restrict__ gw, const float* __restrict__ gb,
                                float* __restrict__ sca, float* __restrict__ shf) {
  int idx = blockIdx.x * 256 + threadIdx.x;
  int b = idx >> 9, c = idx & 511;
  int bg = b * NGROUPS + (c >> 4);
  float s = 0.f, ss = 0.f;
#pragma unroll
  for (int t = 0; t < 8; ++t) {
    float2 p = gpart[bg * 8 + t];
    s += p.x; ss += p.y;
  }
  const float N = (float)(CPG * HWSZ);
  float mu = s / N;
  float var = ss / N - mu * mu;
  float inv = rsqrtf(var + 1e-6f);
  float a = inv * gw[c];
  sca[idx] = a;
  shf[idx] = gb[c] - mu * a;
}

// ---------------- weights f32 -> bf16 (once) ----------------
__global__ void wconv_kernel(const float* __restrict__ qw, const float* __restrict__ kw,
                             const float* __restrict__ vw,
                             bf16* __restrict__ wq, bf16* __restrict__ wk, bf16* __restrict__ wv) {
  int i = blockIdx.x * 256 + threadIdx.x;
  wq[i] = f2b(qw[i]);
  wk[i] = f2b(kw[i]);
  wv[i] = f2b(vw[i]);
}

// ---------------- h_apply: hT[p][c] = bf16(sca[c]*x[b,c,p]+shf[c]) (transpose) -------
__global__ void h_apply_kernel(const float* __restrict__ x, const float* __restrict__ sca,
                               const float* __restrict__ shf, bf16* __restrict__ hT, int b0) {
  int p0 = blockIdx.x * 64, c0 = blockIdx.y * 64;
  int b = b0 + blockIdx.z;
  bf16* hTb = hT + (size_t)blockIdx.z * PER;
  __shared__ bf16 lt[64][66];
  int t = threadIdx.x;
  int pp = (t & 15) * 4, ccb = t >> 4;
#pragma unroll
  for (int it = 0; it < 4; ++it) {
    int cc = ccb + it * 16;
    int c = c0 + cc;
    float a = sca[b * CH + c], s = shf[b * CH + c];
    const float4 xv = *(const float4*)(x + ((size_t)(b * CH + c)) * HWSZ + p0 + pp);
    lt[cc][pp] = f2b(a * xv.x + s);
    lt[cc][pp + 1] = f2b(a * xv.y + s);
    lt[cc][pp + 2] = f2b(a * xv.z + s);
    lt[cc][pp + 3] = f2b(a * xv.w + s);
  }
  __syncthreads();
  int cc = (t & 15) * 4;
#pragma unroll
  for (int it = 0; it < 4; ++it) {
    int pr = (t >> 4) + it * 16;
    u16x4 o;
#pragma unroll
    for (int j = 0; j < 4; ++j) o[j] = *(const unsigned short*)&lt[cc + j][pr];
    *(u16x4*)(hTb + (size_t)(p0 + pr) * CH + c0 + cc) = o;
  }
}

// ======================= shared pipelined GEMM skeleton =======================
// r1/r6-verified skeleton (session best 351us total, 0 bank conflicts):
// 128x128 tile, BK=64, 2x32KB double-buffered LDS, counted vmcnt(8).
// Staging: linear LDS dest + XOR-swizzled GLOBAL source granule:
// LDS[row][g] = global[row][g ^ (row&7)] (rows are 128 B = 8 x 16B granules);
// fragment ds_read_b128 applies the same XOR -> conflict-free.
// Pipeline per K-step t: issue STAGE(t+1) -> s_waitcnt vmcnt(8) -> s_barrier
// -> ds_read+MFMA -> s_barrier. vmcnt(0) only on the final peel.
// r13 lesson: attn store pattern does NOT affect WRITE_SIZE (147MB is
// structural L2-writeback accounting) — keep the direct scatter epilogue.

__device__ __forceinline__ void mm_step(const bf16* la, const bf16* lb,
                                        f32x4 acc[4][4], int wm, int wn,
                                        int quad, int tm) {
#pragma unroll
  for (int kk = 0; kk < 2; ++kk) {
    const int go = ((kk * 4 + quad) ^ (tm & 7)) * 8;  // swizzled granule offset
    short8 aF[4], bF[4];
#pragma unroll
    for (int mt = 0; mt < 4; ++mt) {
      aF[mt] = *(const short8*)(la + (wm + mt * 16 + tm) * 64 + go);
      bF[mt] = *(const short8*)(lb + (wn + mt * 16 + tm) * 64 + go);
    }
#pragma unroll
    for (int mt = 0; mt < 4; ++mt)
#pragma unroll
      for (int nt = 0; nt < 4; ++nt)
        acc[mt][nt] = __builtin_amdgcn_mfma_f32_16x16x32_bf16(aF[mt], bF[nt],
                                                              acc[mt][nt], 0, 0, 0);
  }
}

#define MFMA_VARS()                                   \
  int tid = threadIdx.x;                              \
  int l = tid & 63, w = tid >> 6;                     \
  int quad = l >> 4, tm = l & 15;                     \
  int wm = (w & 1) * 64, wn = (w >> 1) * 64;          \
  int rr = l >> 3;                                    \
  int swz = ((l & 7) ^ rr) * 8;                       \
  bf16* stbase = smem + w * 2048

#define MSTAGE(bufsel, koff)                          \
  do {                                                \
    bf16* _d = stbase + (bufsel) * 16384;             \
    GLL16(sA0 + (koff), _d);                          \
    GLL16(sA1 + (koff), _d + 512);                    \
    GLL16(sA2 + (koff), _d + 1024);                   \
    GLL16(sA3 + (koff), _d + 1536);                   \
    GLL16(sB0 + (koff), _d + 8192);                   \
    GLL16(sB1 + (koff), _d + 8704);                   \
    GLL16(sB2 + (koff), _d + 9216);                   \
    GLL16(sB3 + (koff), _d + 9728);                   \
  } while (0)

#define MKLOOP(NS)                                                       \
  do {                                                                   \
    MSTAGE(0, 0);                                                        \
    for (int _t = 0; _t < (NS); ++_t) {                                  \
      if (_t + 1 < (NS)) {                                               \
        MSTAGE((_t + 1) & 1, (_t + 1) * 64);                             \
        asm volatile("s_waitcnt vmcnt(8)" ::: "memory");                 \
      } else {                                                           \
        asm volatile("s_waitcnt vmcnt(0)" ::: "memory");                 \
      }                                                                  \
      __builtin_amdgcn_s_barrier();                                      \
      mm_step(smem + (_t & 1) * 16384, smem + (_t & 1) * 16384 + 8192,   \
              acc, wm, wn, quad, tm);                                    \
      __builtin_amdgcn_s_barrier();                                      \
    }                                                                    \
  } while (0)

// ---------------- QKV via MFMA (NT), pipelined BK=64, batched ----------------
__global__ __launch_bounds__(256) void qkv_mfma(const bf16* __restrict__ hT,
                                                const bf16* __restrict__ wq,
                                                const bf16* __restrict__ wk,
                                                const bf16* __restrict__ wv,
                                                const float* __restrict__ qb,
                                                const float* __restrict__ kb,
                                                const float* __restrict__ vb,
                                                bf16* __restrict__ qT, bf16* __restrict__ kT,
                                                bf16* __restrict__ v) {
  int p0 = blockIdx.x * 128;
  int o0 = blockIdx.y * 128;
  int bz = blockIdx.z / 3, z = blockIdx.z % 3;
  const bf16* W = z == 0 ? wq : (z == 1 ? wk : wv);
  const float* bias = z == 0 ? qb : (z == 1 ? kb : vb);
  const bf16* hTb = hT + (size_t)bz * PER;
  __shared__ __align__(16) bf16 smem[32768];  // 2 bufs x (A 8192 | B 8192)
  MFMA_VARS();
  const bf16* sA0 = hTb + (size_t)(p0 + w * 32 + rr) * CH + swz;
  const bf16* sA1 = sA0 + (size_t)8 * CH;
  const bf16* sA2 = sA0 + (size_t)16 * CH;
  const bf16* sA3 = sA0 + (size_t)24 * CH;
  const bf16* sB0 = W + (size_t)(o0 + w * 32 + rr) * CH + swz;
  const bf16* sB1 = sB0 + (size_t)8 * CH;
  const bf16* sB2 = sB0 + (size_t)16 * CH;
  const bf16* sB3 = sB0 + (size_t)24 * CH;
  f32x4 acc[4][4] = {};
  MKLOOP(CH / 64);
  if (z < 2) {
    bf16* outT = (z == 0 ? qT : kT) + (size_t)bz * PER;
#pragma unroll
    for (int nt = 0; nt < 4; ++nt) {
      int o = o0 + wn + nt * 16 + tm;
      float bv = bias[o];
#pragma unroll
      for (int mt = 0; mt < 4; ++mt)
#pragma unroll
        for (int r = 0; r < 4; ++r) {
          int p = p0 + wm + mt * 16 + quad * 4 + r;
          outT[(size_t)p * CH + o] = f2b(acc[mt][nt][r] + bv);
        }
    }
  } else {
    // LDS transpose epilogue: v[o][p]
    bf16* vv = v + (size_t)bz * PER;
    bf16* lt = smem;  // 64 x 136 = 8704 elems (fits in 32768)
    for (int chunk = 0; chunk < 2; ++chunk) {
      __syncthreads();
      if (wn == chunk * 64) {
#pragma unroll
        for (int nt = 0; nt < 4; ++nt) {
          int o = o0 + wn + nt * 16 + tm;
          float bv = bias[o];
#pragma unroll
          for (int mt = 0; mt < 4; ++mt)
#pragma unroll
            for (int r = 0; r < 4; ++r)
              lt[(nt * 16 + tm) * 136 + wm + mt * 16 + quad * 4 + r] = f2b(acc[mt][nt][r] + bv);
        }
      }
      __syncthreads();
      int oo = tid >> 2, ppb = (tid & 3) * 32;
      bf16* dst = vv + (size_t)(o0 + chunk * 64 + oo) * HWSZ + p0 + ppb;
      const bf16* src = lt + oo * 136 + ppb;
#pragma unroll
      for (int q4 = 0; q4 < 4; ++q4)
        *(u16x8*)(dst + q4 * 8) = *(const u16x8*)(src + q4 * 8);
    }
  }
}

// ---------------- S via MFMA (NT), pipelined BK=64, fused exp + row-sum, batched -----
// attn[il][j] = exp(scale * sum_c qT[i][c] kT[j][c]); lsum[il] += row partial sums
// (no max-subtraction: |s*scale| <~ 1.2 for this input distribution — r10-validated)
__global__ __launch_bounds__(256) void s_mfma(const bf16* __restrict__ qT,
                                              const bf16* __restrict__ kT,
                                              bf16* __restrict__ attn,
                                              float* __restrict__ lsum) {
  int j0 = blockIdx.x * 128;
  int il0 = blockIdx.y * 128;
  int bz = blockIdx.z;
  const bf16* qTb = qT + (size_t)bz * PER;
  const bf16* kTb = kT + (size_t)bz * PER;
  bf16* attnb = attn + (size_t)bz * HWSZ * HWSZ;
  float* lsumb = lsum + (size_t)bz * HWSZ;
  __shared__ __align__(16) bf16 smem[32768];
  MFMA_VARS();
  const bf16* sA0 = qTb + (size_t)(il0 + w * 32 + rr) * CH + swz;
  const bf16* sA1 = sA0 + (size_t)8 * CH;
  const bf16* sA2 = sA0 + (size_t)16 * CH;
  const bf16* sA3 = sA0 + (size_t)24 * CH;
  const bf16* sB0 = kTb + (size_t)(j0 + w * 32 + rr) * CH + swz;
  const bf16* sB1 = sB0 + (size_t)8 * CH;
  const bf16* sB2 = sB0 + (size_t)16 * CH;
  const bf16* sB3 = sB0 + (size_t)24 * CH;
  f32x4 acc[4][4] = {};
  MKLOOP(CH / 64);
  const float scale = 0.044194173824159216f;  // 512^-0.5
#pragma unroll
  for (int mt = 0; mt < 4; ++mt)
#pragma unroll
    for (int r = 0; r < 4; ++r) {
      int il = il0 + wm + mt * 16 + quad * 4 + r;
      float rs = 0.f;
#pragma unroll
      for (int nt = 0; nt < 4; ++nt) {
        float p = __expf(acc[mt][nt][r] * scale);
        rs += p;
        attnb[(size_t)il * HWSZ + j0 + wn + nt * 16 + tm] = f2b(p);
      }
      rs += __shfl_xor(rs, 1);
      rs += __shfl_xor(rs, 2);
      rs += __shfl_xor(rs, 4);
      rs += __shfl_xor(rs, 8);
      if (tm == 0) atomicAdd(&lsumb[il], rs);
    }
}

// ---------------- A via MFMA + split-K atomics, pipelined BK=64, batched -------------
__global__ __launch_bounds__(256) void a_mfma(const bf16* __restrict__ v,
                                              const bf16* __restrict__ attn,
                                              float* __restrict__ acc_out,
                                              int KC, int ksplit) {
  int il0 = blockIdx.x * 128;
  int c00 = blockIdx.y * 128;
  int bz = blockIdx.z / ksplit;
  int kbase = (blockIdx.z % ksplit) * KC;
  const bf16* vb = v + (size_t)bz * PER;
  const bf16* attnb = attn + (size_t)bz * HWSZ * HWSZ;
  float* accb = acc_out + (size_t)bz * CH * HWSZ;
  __shared__ __align__(16) bf16 smem[32768];
  MFMA_VARS();
  const bf16* sA0 = vb + (size_t)(c00 + w * 32 + rr) * HWSZ + kbase + swz;
  const bf16* sA1 = sA0 + (size_t)8 * HWSZ;
  const bf16* sA2 = sA0 + (size_t)16 * HWSZ;
  const bf16* sA3 = sA0 + (size_t)24 * HWSZ;
  const bf16* sB0 = attnb + (size_t)(il0 + w * 32 + rr) * HWSZ + kbase + swz;
  const bf16* sB1 = sB0 + (size_t)8 * HWSZ;
  const bf16* sB2 = sB0 + (size_t)16 * HWSZ;
  const bf16* sB3 = sB0 + (size_t)24 * HWSZ;
  f32x4 acc[4][4] = {};
  MKLOOP(KC / 64);
#pragma unroll
  for (int mt = 0; mt < 4; ++mt)
#pragma unroll
    for (int nt = 0; nt < 4; ++nt)
#pragma unroll
      for (int r = 0; r < 4; ++r) {
        int c = c00 + wm + mt * 16 + quad * 4 + r;
        int il = il0 + wn + nt * 16 + tm;
        atomicAdd(&accb[(size_t)c * HWSZ + il], acc[mt][nt][r]);
      }
}

// ---------------- out[b,c,i] = x + acc/lsum, batched ----------------
__global__ void add_kernel(const float* __restrict__ x, const float* __restrict__ acc,
                           const float* __restrict__ lsum, float* __restrict__ out, int b0) {
  int idx = blockIdx.x * 256 + threadIdx.x;
  int b = b0 + blockIdx.y;
  const float* accb = acc + (size_t)blockIdx.y * CH * HWSZ;
  const float* lsumb = lsum + (size_t)blockIdx.y * HWSZ;
  int c = idx >> 10;               // 1024 float4 per row of HWSZ
  int r4 = (idx & 1023) * 4;
  size_t g = ((size_t)(b * CH + c)) * HWSZ + r4;
  const float4 xv = *(const float4*)(x + g);
  const float4 av = *(const float4*)(accb + (size_t)c * HWSZ + r4);
  const float4 lv = *(const float4*)(lsumb + r4);
  float4 o;
  o.x = xv.x + av.x / lv.x;
  o.y = xv.y + av.y / lv.y;
  o.z = xv.z + av.z / lv.z;
  o.w = xv.w + av.w / lv.w;
  *(float4*)(out + g) = o;
}

extern "C" void kernel_launch(void* const* d_in, const int* in_sizes, int n_in,
                              void* d_out, int out_size, void* d_ws, size_t ws_size,
                              hipStream_t stream) {
  const float* x   = (const float*)d_in[0];
  const float* gnw = (const float*)d_in[1];
  const float* gnb = (const float*)d_in[2];
  const float* qw  = (const float*)d_in[3];
  const float* qb  = (const float*)d_in[4];
  const float* kw  = (const float*)d_in[5];
  const float* kb  = (const float*)d_in[6];
  const float* vw  = (const float*)d_in[7];
  const float* vb  = (const float*)d_in[8];
  float* out = (float*)d_out;

  char* ws = (char*)d_ws;
  float* sca = (float*)ws;
  float* shf = sca + BATCH * CH;
  float2* gpart = (float2*)(ws + 16384);
  const size_t wsz = (size_t)CH * CH;
  bf16* wqb = (bf16*)(ws + 32768);
  bf16* wkb = wqb + wsz;
  bf16* wvb = wkb + wsz;
  char* dyn = (char*)(wvb + wsz);
  size_t base_used = (size_t)(dyn - ws);
  // per-live-batch: hT/qT/kT/v (4*PER bf16) + attn (HWSZ^2 bf16) + acc (CH*HWSZ f32) + lsum
  size_t perb = 4 * PER * sizeof(bf16) + (size_t)HWSZ * HWSZ * sizeof(bf16) +
                (size_t)CH * HWSZ * sizeof(float) + (size_t)HWSZ * sizeof(float);
  int nb = (int)(((long long)ws_size - (long long)base_used) / (long long)perb);
  if (nb < 1) nb = 1;
  if (nb > BATCH) nb = BATCH;
  bf16* hT = (bf16*)dyn;
  bf16* qT = hT + (size_t)nb * PER;
  bf16* kT = qT + (size_t)nb * PER;
  bf16* v  = kT + (size_t)nb * PER;
  bf16* attn = v + (size_t)nb * PER;
  float* acc = (float*)(attn + (size_t)nb * HWSZ * HWSZ);
  float* lsum = acc + (size_t)nb * CH * HWSZ;

  gn_part_kernel<<<dim3(BATCH * NGROUPS * 8), 256, 0, stream>>>(x, gpart);
  gn_final_kernel<<<dim3(8), 256, 0, stream>>>(gpart, gnw, gnb, sca, shf);
  wconv_kernel<<<dim3(wsz / 256), 256, 0, stream>>>(qw, kw, vw, wqb, wkb, wvb);
  for (int b0 = 0; b0 < BATCH; b0 += nb) {
    int nbc = BATCH - b0 < nb ? BATCH - b0 : nb;
    h_apply_kernel<<<dim3(HWSZ / 64, CH / 64, nbc), 256, 0, stream>>>(x, sca, shf, hT, b0);
    qkv_mfma<<<dim3(HWSZ / 128, CH / 128, 3 * nbc), 256, 0, stream>>>(hT, wqb, wkb, wvb,
                                                                      qb, kb, vb, qT, kT, v);
    hipMemsetAsync(acc, 0, (size_t)nbc * CH * HWSZ * sizeof(float), stream);
    hipMemsetAsync(lsum, 0, (size_t)nbc * HWSZ * sizeof(float), stream);
    // ksplit=4 -> KC=1024 -> 16 K-steps of BK=64 (r1/r6's proven per-block shape);
    // r12 A/B: ksplit=2 neutral-to-worse. Keep 4.
    int ksplit = 1024 / (32 * 4 * nbc);
    if (ksplit < 1) ksplit = 1;
    if (ksplit > 4) ksplit = 4;
    while (ksplit & (ksplit - 1)) --ksplit;
    int KC = HWSZ / ksplit;
    s_mfma<<<dim3(HWSZ / 128, HWSZ / 128, nbc), 256, 0, stream>>>(qT, kT, attn, lsum);
    a_mfma<<<dim3(HWSZ / 128, CH / 128, ksplit * nbc), 256, 0, stream>>>(v, attn, acc, KC, ksplit);
    add_kernel<<<dim3((CH * HWSZ) / 1024, nbc), 256, 0, stream>>>(x, acc, lsum, out, b0);
  }
}

// Round 15
// 319.740 us; speedup vs baseline: 1.1784x; 1.1079x over previous
//
#include <hip/hip_runtime.h>
#include <hip/hip_bf16.h>

typedef __hip_bfloat16 bf16;
typedef __attribute__((ext_vector_type(8))) short short8;   // 8 bf16 MFMA frag
typedef __attribute__((ext_vector_type(4))) float f32x4;    // MFMA acc
typedef __attribute__((ext_vector_type(8))) unsigned short u16x8;
typedef __attribute__((ext_vector_type(4))) unsigned short u16x4;

#define HWSZ 4096
#define CH 512
#define BATCH 4
#define NGROUPS 32
#define CPG 16
#define PER ((size_t)CH * HWSZ)
#define JL 4   // j-tiles per s_mfma block (prologue/epilogue amortization)

// async global->LDS, 16 B per lane; LDS dest is wave-uniform base + lane*16
#define GLL16(gp, lp)                                                         \
  __builtin_amdgcn_global_load_lds(                                           \
      (const __attribute__((address_space(1))) void*)(gp),                    \
      (__attribute__((address_space(3))) void*)(lp), 16, 0, 0)

__device__ __forceinline__ float b2f(bf16 v) { return __bfloat162float(v); }
__device__ __forceinline__ bf16 f2b(float v) { return __float2bfloat16(v); }

// ---------------- GN stage 1: partial sums, 8 chunks per (b,g) ----------------
__global__ void gn_part_kernel(const float* __restrict__ x, float2* __restrict__ gpart) {
  int bg = blockIdx.x >> 3, chunk = blockIdx.x & 7;
  size_t base = (size_t)bg * (CPG * HWSZ) + (size_t)chunk * 8192;
  int tid = threadIdx.x;
  float s = 0.f, ss = 0.f;
  const float4* xp = (const float4*)(x + base);
#pragma unroll
  for (int it = 0; it < 8; ++it) {
    float4 v = xp[tid + it * 256];
    s += v.x + v.y + v.z + v.w;
    ss += v.x * v.x + v.y * v.y + v.z * v.z + v.w * v.w;
  }
  __shared__ float rs[256], rss[256];
  rs[tid] = s; rss[tid] = ss;
  __syncthreads();
  for (int off = 128; off > 0; off >>= 1) {
    if (tid < off) { rs[tid] += rs[tid + off]; rss[tid] += rss[tid + off]; }
    __syncthreads();
  }
  if (tid == 0) gpart[blockIdx.x] = make_float2(rs[0], rss[0]);
}

// ---------------- GN stage 2: per-(b,c) scale/shift ----------------
__global__ void gn_final_kernel(const float2* __restrict__ gpart,
                                const float* __restrict__ gw, const float* __restrict__ gb,
                                float* __restrict__ sca, float* __restrict__ shf) {
  int idx = blockIdx.x * 256 + threadIdx.x;
  int b = idx >> 9, c = idx & 511;
  int bg = b * NGROUPS + (c >> 4);
  float s = 0.f, ss = 0.f;
#pragma unroll
  for (int t = 0; t < 8; ++t) {
    float2 p = gpart[bg * 8 + t];
    s += p.x; ss += p.y;
  }
  const float N = (float)(CPG * HWSZ);
  float mu = s / N;
  float var = ss / N - mu * mu;
  float inv = rsqrtf(var + 1e-6f);
  float a = inv * gw[c];
  sca[idx] = a;
  shf[idx] = gb[c] - mu * a;
}

// ---------------- weights f32 -> bf16 (once) ----------------
__global__ void wconv_kernel(const float* __restrict__ qw, const float* __restrict__ kw,
                             const float* __restrict__ vw,
                             bf16* __restrict__ wq, bf16* __restrict__ wk, bf16* __restrict__ wv) {
  int i = blockIdx.x * 256 + threadIdx.x;
  wq[i] = f2b(qw[i]);
  wk[i] = f2b(kw[i]);
  wv[i] = f2b(vw[i]);
}

// ---------------- h_apply: hT[p][c] = bf16(sca[c]*x[b,c,p]+shf[c]) (transpose) -------
__global__ void h_apply_kernel(const float* __restrict__ x, const float* __restrict__ sca,
                               const float* __restrict__ shf, bf16* __restrict__ hT, int b0) {
  int p0 = blockIdx.x * 64, c0 = blockIdx.y * 64;
  int b = b0 + blockIdx.z;
  bf16* hTb = hT + (size_t)blockIdx.z * PER;
  __shared__ bf16 lt[64][66];
  int t = threadIdx.x;
  int pp = (t & 15) * 4, ccb = t >> 4;
#pragma unroll
  for (int it = 0; it < 4; ++it) {
    int cc = ccb + it * 16;
    int c = c0 + cc;
    float a = sca[b * CH + c], s = shf[b * CH + c];
    const float4 xv = *(const float4*)(x + ((size_t)(b * CH + c)) * HWSZ + p0 + pp);
    lt[cc][pp] = f2b(a * xv.x + s);
    lt[cc][pp + 1] = f2b(a * xv.y + s);
    lt[cc][pp + 2] = f2b(a * xv.z + s);
    lt[cc][pp + 3] = f2b(a * xv.w + s);
  }
  __syncthreads();
  int cc = (t & 15) * 4;
#pragma unroll
  for (int it = 0; it < 4; ++it) {
    int pr = (t >> 4) + it * 16;
    u16x4 o;
#pragma unroll
    for (int j = 0; j < 4; ++j) o[j] = *(const unsigned short*)&lt[cc + j][pr];
    *(u16x4*)(hTb + (size_t)(p0 + pr) * CH + c0 + cc) = o;
  }
}

// ======================= shared pipelined GEMM skeleton =======================
// r1/r6-verified (351us best, 0 bank conflicts): 128x128 tile, BK=64, 2x32KB
// dbuf LDS, counted vmcnt(8), source-granule XOR swizzle
// LDS[row][g] = global[row][g ^ (row&7)] -> conflict-free ds_read_b128.

__device__ __forceinline__ void mm_step(const bf16* la, const bf16* lb,
                                        f32x4 acc[4][4], int wm, int wn,
                                        int quad, int tm) {
#pragma unroll
  for (int kk = 0; kk < 2; ++kk) {
    const int go = ((kk * 4 + quad) ^ (tm & 7)) * 8;  // swizzled granule offset
    short8 aF[4], bF[4];
#pragma unroll
    for (int mt = 0; mt < 4; ++mt) {
      aF[mt] = *(const short8*)(la + (wm + mt * 16 + tm) * 64 + go);
      bF[mt] = *(const short8*)(lb + (wn + mt * 16 + tm) * 64 + go);
    }
#pragma unroll
    for (int mt = 0; mt < 4; ++mt)
#pragma unroll
      for (int nt = 0; nt < 4; ++nt)
        acc[mt][nt] = __builtin_amdgcn_mfma_f32_16x16x32_bf16(aF[mt], bF[nt],
                                                              acc[mt][nt], 0, 0, 0);
  }
}

#define MFMA_VARS()                                   \
  int tid = threadIdx.x;                              \
  int l = tid & 63, w = tid >> 6;                     \
  int quad = l >> 4, tm = l & 15;                     \
  int wm = (w & 1) * 64, wn = (w >> 1) * 64;          \
  int rr = l >> 3;                                    \
  int swz = ((l & 7) ^ rr) * 8;                       \
  bf16* stbase = smem + w * 2048

#define MSTAGE(bufsel, koff)                          \
  do {                                                \
    bf16* _d = stbase + (bufsel) * 16384;             \
    GLL16(sA0 + (koff), _d);                          \
    GLL16(sA1 + (koff), _d + 512);                    \
    GLL16(sA2 + (koff), _d + 1024);                   \
    GLL16(sA3 + (koff), _d + 1536);                   \
    GLL16(sB0 + (koff), _d + 8192);                   \
    GLL16(sB1 + (koff), _d + 8704);                   \
    GLL16(sB2 + (koff), _d + 9216);                   \
    GLL16(sB3 + (koff), _d + 9728);                   \
  } while (0)

#define MKLOOP(NS)                                                       \
  do {                                                                   \
    MSTAGE(0, 0);                                                        \
    for (int _t = 0; _t < (NS); ++_t) {                                  \
      if (_t + 1 < (NS)) {                                               \
        MSTAGE((_t + 1) & 1, (_t + 1) * 64);                             \
        asm volatile("s_waitcnt vmcnt(8)" ::: "memory");                 \
      } else {                                                           \
        asm volatile("s_waitcnt vmcnt(0)" ::: "memory");                 \
      }                                                                  \
      __builtin_amdgcn_s_barrier();                                      \
      mm_step(smem + (_t & 1) * 16384, smem + (_t & 1) * 16384 + 8192,   \
              acc, wm, wn, quad, tm);                                    \
      __builtin_amdgcn_s_barrier();                                      \
    }                                                                    \
  } while (0)

// ---------------- QKV via MFMA (NT), pipelined BK=64, batched ----------------
__global__ __launch_bounds__(256) void qkv_mfma(const bf16* __restrict__ hT,
                                                const bf16* __restrict__ wq,
                                                const bf16* __restrict__ wk,
                                                const bf16* __restrict__ wv,
                                                const float* __restrict__ qb,
                                                const float* __restrict__ kb,
                                                const float* __restrict__ vb,
                                                bf16* __restrict__ qT, bf16* __restrict__ kT,
                                                bf16* __restrict__ v) {
  int p0 = blockIdx.x * 128;
  int o0 = blockIdx.y * 128;
  int bz = blockIdx.z / 3, z = blockIdx.z % 3;
  const bf16* W = z == 0 ? wq : (z == 1 ? wk : wv);
  const float* bias = z == 0 ? qb : (z == 1 ? kb : vb);
  const bf16* hTb = hT + (size_t)bz * PER;
  __shared__ __align__(16) bf16 smem[32768];  // 2 bufs x (A 8192 | B 8192)
  MFMA_VARS();
  const bf16* sA0 = hTb + (size_t)(p0 + w * 32 + rr) * CH + swz;
  const bf16* sA1 = sA0 + (size_t)8 * CH;
  const bf16* sA2 = sA0 + (size_t)16 * CH;
  const bf16* sA3 = sA0 + (size_t)24 * CH;
  const bf16* sB0 = W + (size_t)(o0 + w * 32 + rr) * CH + swz;
  const bf16* sB1 = sB0 + (size_t)8 * CH;
  const bf16* sB2 = sB0 + (size_t)16 * CH;
  const bf16* sB3 = sB0 + (size_t)24 * CH;
  f32x4 acc[4][4] = {};
  MKLOOP(CH / 64);
  if (z < 2) {
    bf16* outT = (z == 0 ? qT : kT) + (size_t)bz * PER;
#pragma unroll
    for (int nt = 0; nt < 4; ++nt) {
      int o = o0 + wn + nt * 16 + tm;
      float bv = bias[o];
#pragma unroll
      for (int mt = 0; mt < 4; ++mt)
#pragma unroll
        for (int r = 0; r < 4; ++r) {
          int p = p0 + wm + mt * 16 + quad * 4 + r;
          outT[(size_t)p * CH + o] = f2b(acc[mt][nt][r] + bv);
        }
    }
  } else {
    // LDS transpose epilogue: v[o][p]
    bf16* vv = v + (size_t)bz * PER;
    bf16* lt = smem;  // 64 x 136 = 8704 elems (fits in 32768)
    for (int chunk = 0; chunk < 2; ++chunk) {
      __syncthreads();
      if (wn == chunk * 64) {
#pragma unroll
        for (int nt = 0; nt < 4; ++nt) {
          int o = o0 + wn + nt * 16 + tm;
          float bv = bias[o];
#pragma unroll
          for (int mt = 0; mt < 4; ++mt)
#pragma unroll
            for (int r = 0; r < 4; ++r)
              lt[(nt * 16 + tm) * 136 + wm + mt * 16 + quad * 4 + r] = f2b(acc[mt][nt][r] + bv);
        }
      }
      __syncthreads();
      int oo = tid >> 2, ppb = (tid & 3) * 32;
      bf16* dst = vv + (size_t)(o0 + chunk * 64 + oo) * HWSZ + p0 + ppb;
      const bf16* src = lt + oo * 136 + ppb;
#pragma unroll
      for (int q4 = 0; q4 < 4; ++q4)
        *(u16x8*)(dst + q4 * 8) = *(const u16x8*)(src + q4 * 8);
    }
  }
}

// ---------------- S via MFMA, j-looped (JL=4), pipelined BK=64, batched --------------
// attn[il][j] = exp(scale * sum_c qT[i][c] kT[j][c]); lsum[il] += row partial sums.
// r15: each block computes JL=4 consecutive j-tiles. K=512 means only 8 K-steps
// per tile — prologue (~900cy cold stage) + serial epilogue dominated per-block
// time. Now: next-j's first stage is issued BEFORE the epilogue (T14 overlap:
// exp/rowsum/store VALU hides the stage flight), qT A-panel re-staged L2-hot.
// vmcnt audit: epilogue stores interpose -> next t=0's vmcnt(8) over-waits
// (safe); buf0 WAR covered by the t=6-end barrier exactly as in MKLOOP.
#define SSTAGE(bufsel, koff, jof)                      \
  do {                                                 \
    bf16* _d = stbase + (bufsel) * 16384;              \
    GLL16(sA0 + (koff), _d);                           \
    GLL16(sA1 + (koff), _d + 512);                     \
    GLL16(sA2 + (koff), _d + 1024);                    \
    GLL16(sA3 + (koff), _d + 1536);                    \
    GLL16(sB0 + (jof) + (koff), _d + 8192);            \
    GLL16(sB1 + (jof) + (koff), _d + 8704);            \
    GLL16(sB2 + (jof) + (koff), _d + 9216);            \
    GLL16(sB3 + (jof) + (koff), _d + 9728);            \
  } while (0)

__global__ __launch_bounds__(256) void s_mfma(const bf16* __restrict__ qT,
                                              const bf16* __restrict__ kT,
                                              bf16* __restrict__ attn,
                                              float* __restrict__ lsum) {
  int j0base = blockIdx.x * (128 * JL);
  int il0 = blockIdx.y * 128;
  int bz = blockIdx.z;
  const bf16* qTb = qT + (size_t)bz * PER;
  const bf16* kTb = kT + (size_t)bz * PER;
  bf16* attnb = attn + (size_t)bz * HWSZ * HWSZ;
  float* lsumb = lsum + (size_t)bz * HWSZ;
  __shared__ __align__(16) bf16 smem[32768];
  MFMA_VARS();
  const bf16* sA0 = qTb + (size_t)(il0 + w * 32 + rr) * CH + swz;
  const bf16* sA1 = sA0 + (size_t)8 * CH;
  const bf16* sA2 = sA0 + (size_t)16 * CH;
  const bf16* sA3 = sA0 + (size_t)24 * CH;
  const bf16* sB0 = kTb + (size_t)(j0base + w * 32 + rr) * CH + swz;
  const bf16* sB1 = sB0 + (size_t)8 * CH;
  const bf16* sB2 = sB0 + (size_t)16 * CH;
  const bf16* sB3 = sB0 + (size_t)24 * CH;
  const float scale = 0.044194173824159216f;  // 512^-0.5
  SSTAGE(0, 0, 0);
  for (int jj = 0; jj < JL; ++jj) {
    const size_t jof = (size_t)jj * 128 * CH;
    const size_t jofn = (size_t)(jj + 1) * 128 * CH;
    f32x4 acc[4][4] = {};
    for (int _t = 0; _t < 8; ++_t) {
      if (_t + 1 < 8) {
        SSTAGE((_t + 1) & 1, (_t + 1) * 64, jof);
        asm volatile("s_waitcnt vmcnt(8)" ::: "memory");
      } else if (jj + 1 < JL) {
        SSTAGE(0, 0, jofn);  // next j-tile's t=0 -> buf0, flies across epilogue
        asm volatile("s_waitcnt vmcnt(8)" ::: "memory");
      } else {
        asm volatile("s_waitcnt vmcnt(0)" ::: "memory");
      }
      __builtin_amdgcn_s_barrier();
      mm_step(smem + (_t & 1) * 16384, smem + (_t & 1) * 16384 + 8192,
              acc, wm, wn, quad, tm);
      __builtin_amdgcn_s_barrier();
    }
    int j0 = j0base + jj * 128;
#pragma unroll
    for (int mt = 0; mt < 4; ++mt)
#pragma unroll
      for (int r = 0; r < 4; ++r) {
        int il = il0 + wm + mt * 16 + quad * 4 + r;
        float rs = 0.f;
#pragma unroll
        for (int nt = 0; nt < 4; ++nt) {
          float p = __expf(acc[mt][nt][r] * scale);
          rs += p;
          attnb[(size_t)il * HWSZ + j0 + wn + nt * 16 + tm] = f2b(p);
        }
        rs += __shfl_xor(rs, 1);
        rs += __shfl_xor(rs, 2);
        rs += __shfl_xor(rs, 4);
        rs += __shfl_xor(rs, 8);
        if (tm == 0) atomicAdd(&lsumb[il], rs);
      }
  }
}

// -------- A via MFMA, ksplit=1, fused epilogue out = x + acc/lsum, batched ----------
// r12 evidence: ksplit=1 at nb=4 (512 blocks, 2/CU) is duration-neutral for
// a_mfma -> split-K atomics, the 32MB acc memset, and add_kernel are all
// unnecessary. Fused epilogue reads x/lsum and writes out directly (f32).
__global__ __launch_bounds__(256) void a_mfma_fused(const bf16* __restrict__ v,
                                                    const bf16* __restrict__ attn,
                                                    const float* __restrict__ x,
                                                    const float* __restrict__ lsum,
                                                    float* __restrict__ out, int b0) {
  int il0 = blockIdx.x * 128;
  int c00 = blockIdx.y * 128;
  int bz = blockIdx.z;
  const bf16* vb = v + (size_t)bz * PER;
  const bf16* attnb = attn + (size_t)bz * HWSZ * HWSZ;
  const float* lsumb = lsum + (size_t)bz * HWSZ;
  const float* xb = x + (size_t)(b0 + bz) * CH * HWSZ;
  float* outb = out + (size_t)(b0 + bz) * CH * HWSZ;
  __shared__ __align__(16) bf16 smem[32768];
  MFMA_VARS();
  const bf16* sA0 = vb + (size_t)(c00 + w * 32 + rr) * HWSZ + swz;
  const bf16* sA1 = sA0 + (size_t)8 * HWSZ;
  const bf16* sA2 = sA0 + (size_t)16 * HWSZ;
  const bf16* sA3 = sA0 + (size_t)24 * HWSZ;
  const bf16* sB0 = attnb + (size_t)(il0 + w * 32 + rr) * HWSZ + swz;
  const bf16* sB1 = sB0 + (size_t)8 * HWSZ;
  const bf16* sB2 = sB0 + (size_t)16 * HWSZ;
  const bf16* sB3 = sB0 + (size_t)24 * HWSZ;
  f32x4 acc[4][4] = {};
  MKLOOP(HWSZ / 64);
#pragma unroll
  for (int nt = 0; nt < 4; ++nt) {
    int il = il0 + wn + nt * 16 + tm;
    float rl = 1.0f / lsumb[il];
#pragma unroll
    for (int mt = 0; mt < 4; ++mt)
#pragma unroll
      for (int r = 0; r < 4; ++r) {
        int c = c00 + wm + mt * 16 + quad * 4 + r;
        size_t g = (size_t)c * HWSZ + il;
        outb[g] = xb[g] + acc[mt][nt][r] * rl;
      }
  }
}

// ---------------- A via MFMA + split-K atomics (fallback, nbc==1) ----------------
__global__ __launch_bounds__(256) void a_mfma(const bf16* __restrict__ v,
                                              const bf16* __restrict__ attn,
                                              float* __restrict__ acc_out,
                                              int KC, int ksplit) {
  int il0 = blockIdx.x * 128;
  int c00 = blockIdx.y * 128;
  int bz = blockIdx.z / ksplit;
  int kbase = (blockIdx.z % ksplit) * KC;
  const bf16* vb = v + (size_t)bz * PER;
  const bf16* attnb = attn + (size_t)bz * HWSZ * HWSZ;
  float* accb = acc_out + (size_t)bz * CH * HWSZ;
  __shared__ __align__(16) bf16 smem[32768];
  MFMA_VARS();
  const bf16* sA0 = vb + (size_t)(c00 + w * 32 + rr) * HWSZ + kbase + swz;
  const bf16* sA1 = sA0 + (size_t)8 * HWSZ;
  const bf16* sA2 = sA0 + (size_t)16 * HWSZ;
  const bf16* sA3 = sA0 + (size_t)24 * HWSZ;
  const bf16* sB0 = attnb + (size_t)(il0 + w * 32 + rr) * HWSZ + kbase + swz;
  const bf16* sB1 = sB0 + (size_t)8 * HWSZ;
  const bf16* sB2 = sB0 + (size_t)16 * HWSZ;
  const bf16* sB3 = sB0 + (size_t)24 * HWSZ;
  f32x4 acc[4][4] = {};
  MKLOOP(KC / 64);
#pragma unroll
  for (int mt = 0; mt < 4; ++mt)
#pragma unroll
    for (int nt = 0; nt < 4; ++nt)
#pragma unroll
      for (int r = 0; r < 4; ++r) {
        int c = c00 + wm + mt * 16 + quad * 4 + r;
        int il = il0 + wn + nt * 16 + tm;
        atomicAdd(&accb[(size_t)c * HWSZ + il], acc[mt][nt][r]);
      }
}

// ---------------- out[b,c,i] = x + acc/lsum (fallback path only) ----------------
__global__ void add_kernel(const float* __restrict__ x, const float* __restrict__ acc,
                           const float* __restrict__ lsum, float* __restrict__ out, int b0) {
  int idx = blockIdx.x * 256 + threadIdx.x;
  int b = b0 + blockIdx.y;
  const float* accb = acc + (size_t)blockIdx.y * CH * HWSZ;
  const float* lsumb = lsum + (size_t)blockIdx.y * HWSZ;
  int c = idx >> 10;               // 1024 float4 per row of HWSZ
  int r4 = (idx & 1023) * 4;
  size_t g = ((size_t)(b * CH + c)) * HWSZ + r4;
  const float4 xv = *(const float4*)(x + g);
  const float4 av = *(const float4*)(accb + (size_t)c * HWSZ + r4);
  const float4 lv = *(const float4*)(lsumb + r4);
  float4 o;
  o.x = xv.x + av.x / lv.x;
  o.y = xv.y + av.y / lv.y;
  o.z = xv.z + av.z / lv.z;
  o.w = xv.w + av.w / lv.w;
  *(float4*)(out + g) = o;
}

extern "C" void kernel_launch(void* const* d_in, const int* in_sizes, int n_in,
                              void* d_out, int out_size, void* d_ws, size_t ws_size,
                              hipStream_t stream) {
  const float* x   = (const float*)d_in[0];
  const float* gnw = (const float*)d_in[1];
  const float* gnb = (const float*)d_in[2];
  const float* qw  = (const float*)d_in[3];
  const float* qb  = (const float*)d_in[4];
  const float* kw  = (const float*)d_in[5];
  const float* kb  = (const float*)d_in[6];
  const float* vw  = (const float*)d_in[7];
  const float* vb  = (const float*)d_in[8];
  float* out = (float*)d_out;

  char* ws = (char*)d_ws;
  float* sca = (float*)ws;
  float* shf = sca + BATCH * CH;
  float2* gpart = (float2*)(ws + 16384);
  const size_t wsz = (size_t)CH * CH;
  bf16* wqb = (bf16*)(ws + 32768);
  bf16* wkb = wqb + wsz;
  bf16* wvb = wkb + wsz;
  char* dyn = (char*)(wvb + wsz);
  size_t base_used = (size_t)(dyn - ws);
  // per-live-batch: hT/qT/kT/v (4*PER bf16) + attn (HWSZ^2 bf16) + acc (CH*HWSZ f32) + lsum
  size_t perb = 4 * PER * sizeof(bf16) + (size_t)HWSZ * HWSZ * sizeof(bf16) +
                (size_t)CH * HWSZ * sizeof(float) + (size_t)HWSZ * sizeof(float);
  int nb = (int)(((long long)ws_size - (long long)base_used) / (long long)perb);
  if (nb < 1) nb = 1;
  if (nb > BATCH) nb = BATCH;
  bf16* hT = (bf16*)dyn;
  bf16* qT = hT + (size_t)nb * PER;
  bf16* kT = qT + (size_t)nb * PER;
  bf16* v  = kT + (size_t)nb * PER;
  bf16* attn = v + (size_t)nb * PER;
  float* acc = (float*)(attn + (size_t)nb * HWSZ * HWSZ);
  float* lsum = acc + (size_t)nb * CH * HWSZ;

  gn_part_kernel<<<dim3(BATCH * NGROUPS * 8), 256, 0, stream>>>(x, gpart);
  gn_final_kernel<<<dim3(8), 256, 0, stream>>>(gpart, gnw, gnb, sca, shf);
  wconv_kernel<<<dim3(wsz / 256), 256, 0, stream>>>(qw, kw, vw, wqb, wkb, wvb);
  for (int b0 = 0; b0 < BATCH; b0 += nb) {
    int nbc = BATCH - b0 < nb ? BATCH - b0 : nb;
    h_apply_kernel<<<dim3(HWSZ / 64, CH / 64, nbc), 256, 0, stream>>>(x, sca, shf, hT, b0);
    qkv_mfma<<<dim3(HWSZ / 128, CH / 128, 3 * nbc), 256, 0, stream>>>(hT, wqb, wkb, wvb,
                                                                      qb, kb, vb, qT, kT, v);
    hipMemsetAsync(lsum, 0, (size_t)nbc * HWSZ * sizeof(float), stream);
    s_mfma<<<dim3(HWSZ / (128 * JL), HWSZ / 128, nbc), 256, 0, stream>>>(qT, kT, attn, lsum);
    if (nbc >= 2) {
      // ksplit=1 path (r12: 512+ blocks at 2/CU duration-neutral): no acc
      // memset, no atomics, add fused into a_mfma's epilogue.
      a_mfma_fused<<<dim3(HWSZ / 128, CH / 128, nbc), 256, 0, stream>>>(v, attn, x, lsum,
                                                                        out, b0);
    } else {
      hipMemsetAsync(acc, 0, (size_t)nbc * CH * HWSZ * sizeof(float), stream);
      int ksplit = 4;
      int KC = HWSZ / ksplit;
      a_mfma<<<dim3(HWSZ / 128, CH / 128, ksplit * nbc), 256, 0, stream>>>(v, attn, acc, KC,
                                                                           ksplit);
      add_kernel<<<dim3((CH * HWSZ) / 1024, nbc), 256, 0, stream>>>(x, acc, lsum, out, b0);
    }
  }
}